// Round 1
// baseline (131.913 us; speedup 1.0000x reference)
//
#include <hip/hip_runtime.h>

#define NRES 512
#define CZ   128
#define CT   64

typedef short bf16x8 __attribute__((ext_vector_type(8)));
typedef short bf16x4 __attribute__((ext_vector_type(4)));
typedef float f32x4  __attribute__((ext_vector_type(4)));

#define MFMA16(a,b,c) __builtin_amdgcn_mfma_f32_16x16x32_bf16((a),(b),(c),0,0,0)

__device__ __forceinline__ unsigned short f2bf(float f){
  unsigned int u = __builtin_bit_cast(unsigned int, f);
  u += 0x7fffu + ((u >> 16) & 1u);
  return (unsigned short)(u >> 16);
}
__device__ __forceinline__ float bf2f(short b){
  return __builtin_bit_cast(float, ((unsigned int)(unsigned short)b) << 16);
}

// ---- weight pre-pack: B-fragments for mfma_f32_16x16x32_bf16 ----
// frag f: lane l, elem j -> B[k = ks*32 + (l>>4)*8 + j][col = nt*16 + (l&15)]
// stored at packed[f*512 + l*8 + j]
// f  0..15: wq (128x64), nt=f>>2, ks=f&3, scale=0.25 (1/sqrt(C_HID) folded in)
// f 16..23: wk (64x64),  nt=(f-16)>>1, ks=(f-16)&1
// f 24..31: wv (64x64),  nt=head=(f-24)>>1, ks=(f-24)&1
// f 32..47: wo (64x128), nt=(f-32)>>1 (0..7), ks=(f-32)&1
__global__ void prep_pack(const float* __restrict__ wq, const float* __restrict__ wk,
                          const float* __restrict__ wv, const float* __restrict__ wo,
                          unsigned short* __restrict__ packed){
  int idx = blockIdx.x * 256 + threadIdx.x;
  if (idx >= 48 * 64) return;
  int f = idx >> 6, lane = idx & 63;
  const float* W; int Ncols, nt, ks; float scale = 1.0f;
  if (f < 16)      { W = wq; Ncols = 64;  nt = f >> 2;        ks = f & 3;        scale = 0.25f; }
  else if (f < 24) { W = wk; Ncols = 64;  nt = (f - 16) >> 1; ks = (f - 16) & 1; }
  else if (f < 32) { W = wv; Ncols = 64;  nt = (f - 24) >> 1; ks = (f - 24) & 1; }
  else             { W = wo; Ncols = 128; nt = (f - 32) >> 1; ks = (f - 32) & 1; }
  int col = nt * 16 + (lane & 15);
  int k0  = ks * 32 + (lane >> 4) * 8;
  unsigned short* dst = packed + (size_t)f * 512 + (size_t)lane * 8;
#pragma unroll
  for (int j = 0; j < 8; ++j)
    dst[j] = f2bf(W[(k0 + j) * Ncols + col] * scale);
}

// LDS map (64 KiB total):
//   [0,16384)      Zb: 64 rows x 128 bf16 (256B rows, swizzled)   -> after Q: u0,u1 (2 x 64x64 bf16)
//   [16384,49152)  Tb: 4 x (64 rows x 64 bf16, 128B rows, swz)    -> after u: O (64x64 bf16) at 16384
//   [49152,65536)  u2,u3 (2 x 64x64 bf16)
#define TB_OFF 16384
#define O_OFF  16384
#define U23_OFF 49152

__launch_bounds__(256, 2)
__global__ void tpa_main(const float* __restrict__ t, const float* __restrict__ z,
                         const float* __restrict__ mask, const float* __restrict__ bo,
                         const unsigned short* __restrict__ packed,
                         float* __restrict__ out){
  __shared__ __align__(16) char smem[65536];

  const int tid  = threadIdx.x;
  const int lane = tid & 63;
  const int w    = tid >> 6;        // wave 0..3 -> rows [16w,16w+16)
  const int b    = blockIdx.x;
  const int i    = b >> 3;          // z-row
  const int j0   = (b & 7) << 6;    // pixel-column tile base

  // ---------------- stage z tile: 64x128 f32 -> bf16 LDS ----------------
  {
    const float4* zg = reinterpret_cast<const float4*>(z + ((size_t)i * NRES + j0) * CZ);
#pragma unroll
    for (int it = 0; it < 8; ++it){
      int f4  = tid + it * 256;       // 0..2047
      int row = f4 >> 5;              // 32 float4 per row
      int fc  = f4 & 31;
      float4 v = zg[f4];
      unsigned int lo = (unsigned int)f2bf(v.x) | ((unsigned int)f2bf(v.y) << 16);
      unsigned int hi = (unsigned int)f2bf(v.z) | ((unsigned int)f2bf(v.w) << 16);
      int addr = row * 256 + ((fc * 8) ^ ((row & 7) << 4));
      *reinterpret_cast<uint2*>(smem + addr) = make_uint2(lo, hi);
    }
  }
  // ---------------- stage t tile: 4 x 64x64 f32 -> bf16 LDS ----------------
  {
#pragma unroll
    for (int it = 0; it < 16; ++it){
      int f4 = tid + it * 256;        // 0..4095
      int s  = f4 >> 10;
      int r6 = f4 & 1023;
      int row = r6 >> 4;              // 16 float4 per row
      int fc  = r6 & 15;
      const float4* tg = reinterpret_cast<const float4*>(
          t + (((size_t)s * NRES + i) * NRES + j0) * CT);
      float4 v = tg[r6];
      unsigned int lo = (unsigned int)f2bf(v.x) | ((unsigned int)f2bf(v.y) << 16);
      unsigned int hi = (unsigned int)f2bf(v.z) | ((unsigned int)f2bf(v.w) << 16);
      int addr = TB_OFF + s * 8192 + row * 128 + ((fc * 8) ^ ((row & 7) << 4));
      *reinterpret_cast<uint2*>(smem + addr) = make_uint2(lo, hi);
    }
  }
  __syncthreads();

  // uniform scalars
  float m0 = mask[0], m1 = mask[1], m2 = mask[2], m3 = mask[3];
  float msum = m0 + m1 + m2 + m3;
  float bias[4] = {1e9f * (m0 - 1.0f), 1e9f * (m1 - 1.0f),
                   1e9f * (m2 - 1.0f), 1e9f * (m3 - 1.0f)};

  const int arow = (w << 4) + (lane & 15);     // A-frag row (M)
  const int ksegb = (lane >> 4) * 16;          // byte offset of 8-elem k group within 64B k-step
#define LOADB(fi) (*reinterpret_cast<const bf16x8*>(packed + (size_t)(fi) * 512 + (size_t)lane * 8))

  // ---------------- P1: Q = Zb @ wq (scaled) ----------------
  f32x4 qf[4];
  {
    bf16x8 za[4];
#pragma unroll
    for (int ks = 0; ks < 4; ++ks){
      int kb = ks * 64 + ksegb;
      za[ks] = *reinterpret_cast<const bf16x8*>(smem + arow * 256 + (kb ^ ((arow & 7) << 4)));
    }
#pragma unroll
    for (int nt = 0; nt < 4; ++nt){
      f32x4 acc = {0.f, 0.f, 0.f, 0.f};
#pragma unroll
      for (int ks = 0; ks < 4; ++ks)
        acc = MFMA16(za[ks], LOADB(nt * 4 + ks), acc);
      qf[nt] = acc;
    }
  }

  // ---------------- P2: per-template K projection + logits ----------------
  f32x4 lg[4][4];   // [s][head], components = 4 rows of this lane's group
#pragma unroll
  for (int s = 0; s < 4; ++s){
    bf16x8 ta[2];
#pragma unroll
    for (int ks = 0; ks < 2; ++ks){
      int kb = ks * 64 + ksegb;
      ta[ks] = *reinterpret_cast<const bf16x8*>(
          smem + TB_OFF + s * 8192 + arow * 128 + (kb ^ ((arow & 7) << 4)));
    }
#pragma unroll
    for (int nt = 0; nt < 4; ++nt){
      f32x4 acc = {0.f, 0.f, 0.f, 0.f};
      acc = MFMA16(ta[0], LOADB(16 + nt * 2 + 0), acc);
      acc = MFMA16(ta[1], LOADB(16 + nt * 2 + 1), acc);
      f32x4 p = acc * qf[nt];
      // sum over the 16 head-dims (16 lanes of this group)
#pragma unroll
      for (int off = 1; off < 16; off <<= 1){
#pragma unroll
        for (int r = 0; r < 4; ++r) p[r] += __shfl_xor(p[r], off);
      }
      lg[s][nt] = p + bias[s];
    }
  }

  // ---------------- P3: softmax over s (in place -> a) ----------------
#pragma unroll
  for (int nt = 0; nt < 4; ++nt){
    f32x4 mx;
#pragma unroll
    for (int r = 0; r < 4; ++r)
      mx[r] = fmaxf(fmaxf(lg[0][nt][r], lg[1][nt][r]), fmaxf(lg[2][nt][r], lg[3][nt][r]));
    f32x4 sum = {0.f, 0.f, 0.f, 0.f};
#pragma unroll
    for (int s = 0; s < 4; ++s){
#pragma unroll
      for (int r = 0; r < 4; ++r) lg[s][nt][r] = __expf(lg[s][nt][r] - mx[r]);
      sum += lg[s][nt];
    }
    f32x4 inv;
#pragma unroll
    for (int r = 0; r < 4; ++r) inv[r] = 1.0f / sum[r];
#pragma unroll
    for (int s = 0; s < 4; ++s) lg[s][nt] *= inv;
  }

  __syncthreads();   // all waves done reading Zb (P1) before u0/u1 overwrite it

  // ---------------- P4: u_h[row,c] = sum_s a[row,h,s] * t_s[row,c] ----------------
  {
    const int g  = lane >> 4, cl = lane & 15;
    const int cb = cl * 8;   // byte offset of this lane's 4 bf16 c-group
#pragma unroll
    for (int r = 0; r < 4; ++r){
      int row = (w << 4) + (g << 2) + r;
      int swzrow = (row & 7) << 4;
      float tv[4][4];
#pragma unroll
      for (int s = 0; s < 4; ++s){
        bf16x4 tq = *reinterpret_cast<const bf16x4*>(
            smem + TB_OFF + s * 8192 + row * 128 + (cb ^ swzrow));
#pragma unroll
        for (int cc = 0; cc < 4; ++cc) tv[s][cc] = bf2f(tq[cc]);
      }
#pragma unroll
      for (int h = 0; h < 4; ++h){
        unsigned int lo, hi;
        float u0 = lg[0][h][r] * tv[0][0] + lg[1][h][r] * tv[1][0] + lg[2][h][r] * tv[2][0] + lg[3][h][r] * tv[3][0];
        float u1 = lg[0][h][r] * tv[0][1] + lg[1][h][r] * tv[1][1] + lg[2][h][r] * tv[2][1] + lg[3][h][r] * tv[3][1];
        float u2 = lg[0][h][r] * tv[0][2] + lg[1][h][r] * tv[1][2] + lg[2][h][r] * tv[2][2] + lg[3][h][r] * tv[3][2];
        float u3 = lg[0][h][r] * tv[0][3] + lg[1][h][r] * tv[1][3] + lg[2][h][r] * tv[2][3] + lg[3][h][r] * tv[3][3];
        lo = (unsigned int)f2bf(u0) | ((unsigned int)f2bf(u1) << 16);
        hi = (unsigned int)f2bf(u2) | ((unsigned int)f2bf(u3) << 16);
        int ubase = (h < 2) ? h * 8192 : U23_OFF + (h - 2) * 8192;
        *reinterpret_cast<uint2*>(smem + ubase + row * 128 + (cb ^ swzrow)) = make_uint2(lo, hi);
      }
    }
  }
  __syncthreads();   // u complete; Tb now dead (O may overwrite its start)

  // ---------------- P5: O[:, h*16:+16] = u_h @ wv_h ----------------
  {
    f32x4 of[4];
#pragma unroll
    for (int h = 0; h < 4; ++h){
      int ubase = (h < 2) ? h * 8192 : U23_OFF + (h - 2) * 8192;
      f32x4 acc = {0.f, 0.f, 0.f, 0.f};
#pragma unroll
      for (int ks = 0; ks < 2; ++ks){
        int kb = ks * 64 + ksegb;
        bf16x8 ua = *reinterpret_cast<const bf16x8*>(
            smem + ubase + arow * 128 + (kb ^ ((arow & 7) << 4)));
        acc = MFMA16(ua, LOADB(24 + h * 2 + ks), acc);
      }
      of[h] = acc;
    }
    // write O (bf16, swizzled) into Tb's first 8 KiB
    const int g = lane >> 4, cl = lane & 15;
#pragma unroll
    for (int h = 0; h < 4; ++h){
#pragma unroll
      for (int r = 0; r < 4; ++r){
        int row = (w << 4) + (g << 2) + r;
        int colb = (h * 16 + cl) * 2;
        *reinterpret_cast<unsigned short*>(
            smem + O_OFF + row * 128 + (colb ^ ((row & 7) << 4))) = f2bf(of[h][r]);
      }
    }
  }
  __syncthreads();

  // ---------------- P6: Out = O @ wo + bo, gated ----------------
  {
    float gate = (msum > 0.0f) ? 1.0f : 0.0f;
    bf16x8 oa[2];
#pragma unroll
    for (int ks = 0; ks < 2; ++ks){
      int kb = ks * 64 + ksegb;
      oa[ks] = *reinterpret_cast<const bf16x8*>(
          smem + O_OFF + arow * 128 + (kb ^ ((arow & 7) << 4)));
    }
    const int g = lane >> 4, cl = lane & 15;
    float* outg = out + ((size_t)i * NRES + j0) * CZ;
#pragma unroll
    for (int nt = 0; nt < 8; ++nt){
      f32x4 acc = {0.f, 0.f, 0.f, 0.f};
      acc = MFMA16(oa[0], LOADB(32 + nt * 2 + 0), acc);
      acc = MFMA16(oa[1], LOADB(32 + nt * 2 + 1), acc);
      int col = nt * 16 + cl;
      float bov = bo[col];
#pragma unroll
      for (int r = 0; r < 4; ++r){
        int lr = (w << 4) + (g << 2) + r;
        outg[(size_t)lr * CZ + col] = (acc[r] + bov) * gate;
      }
    }
  }
}

extern "C" void kernel_launch(void* const* d_in, const int* in_sizes, int n_in,
                              void* d_out, int out_size, void* d_ws, size_t ws_size,
                              hipStream_t stream) {
  const float* t    = (const float*)d_in[0];
  const float* z    = (const float*)d_in[1];
  const float* mask = (const float*)d_in[2];
  const float* wq   = (const float*)d_in[3];
  const float* wk   = (const float*)d_in[4];
  const float* wv   = (const float*)d_in[5];
  const float* wo   = (const float*)d_in[6];
  const float* bo   = (const float*)d_in[7];
  unsigned short* packed = (unsigned short*)d_ws;

  hipLaunchKernelGGL(prep_pack, dim3(12), dim3(256), 0, stream, wq, wk, wv, wo, packed);
  hipLaunchKernelGGL(tpa_main, dim3(4096), dim3(256), 0, stream,
                     t, z, mask, bo, packed, (float*)d_out);
}